// Round 19
// baseline (69219.202 us; speedup 1.0000x reference)
//
#include <hip/hip_runtime.h>
#include <math.h>

#define NSWEEP_MAX 16
#define T2_TOL 2e-7f    // validated r12-r17: output err ~7e-3 << 0.066
#define EPS2 1e-10f     // lambda clamp 1e-5 => lambda^2 clamp 1e-10

// One-sided Jacobi on G = S (SPD), one 64-lane wave per 64x64 matrix, lane l
// holds column l. Packed-fp32 (r16) + FAST-GIVENS scaled columns (algebra
// validated r17):
//   true column g = sqrt(gam)*ghat;
//   ghat' = ghat + al*prhat        al = -t_own*sqrt(pgam/gam)
//   prhat' = prhat + be*ghat_old   be =  t_own*sqrt(gam/pgam)
//   gam *= ccsq, pgam *= ccsq      ccsq = 1/(1+t^2)
// -> ONE pk_fma per v2f per column. |t|<=1 => ccsq >= 1/2; rescale to
// gam=1 at sweep start and mid-sweep keeps gam >= 2^-31 (no denormals).
//
// r18 FAILURE ROOT CAUSE (absmax 25): the permlane self-swaps are inline
// asm; the post-RA hazard recognizer cannot see the lane-crossing op
// INSIDE the asm, so when the scheduler pipelined the rescale loop's
// pr2 writes directly into the swap reads (write pr2[k]; swap pr2[k]
// back-to-back), the HW hazard (VALU write -> permlane read wait states)
// corrupted data. Same class as r14's NaN. FIX: sched_barrier(0) fences
// around each swap re-pair block + s_nop 2 at entry + volatile swaps.
// Within a block, swap k reads a register last written >=31 instructions
// earlier (loops write pr2[0..31] in order, swaps read in order), so only
// the block boundary needs the nop. DPP re-pairs remain builtins
// (compiler-managed hazards). 3 fences/sweep — negligible cost.
//
// GRAY-CODE pairing with maintained partner copy (r11); bitwise
// pair-consistency as r5-r17 (commuted packed fma dot; canonical tau;
// t_own sign-split by isLow; be_p == al_q bitwise via chain invariants).

typedef float v2f __attribute__((ext_vector_type(2)));

__device__ __forceinline__ v2f pkfma(v2f a, v2f b, v2f c) {
    return __builtin_elementwise_fma(a, b, c);
}

template <int CTRL>
__device__ __forceinline__ int dpp1(int x) {
    return __builtin_amdgcn_update_dpp(0, x, CTRL, 0xF, 0xF, true);
}
template <int CTRL>
__device__ __forceinline__ float dppf1(float x) {
    return __int_as_float(dpp1<CTRL>(__float_as_int(x)));
}
template <int CTRL>
__device__ __forceinline__ v2f dppv2(v2f x) {
    v2f r;
    r.x = dppf1<CTRL>(x.x);
    r.y = dppf1<CTRL>(x.y);
    return r;
}
__device__ __forceinline__ float swap16_self(float x) {
    asm volatile("v_permlane16_swap_b32 %0, %0" : "+v"(x));
    return x;  // x[lane] = old x[lane^16]
}
__device__ __forceinline__ float swap32_self(float x) {
    asm volatile("v_permlane32_swap_b32 %0, %0" : "+v"(x));
    return x;  // x[lane] = old x[lane^32]
}
__device__ __forceinline__ v2f swap16v2(v2f x) {
    v2f r;
    r.x = swap16_self(x.x);
    r.y = swap16_self(x.y);
    return r;
}
__device__ __forceinline__ v2f swap32v2(v2f x) {
    v2f r;
    r.x = swap32_self(x.x);
    r.y = swap32_self(x.y);
    return r;
}
__device__ __forceinline__ float rdlane_f(float x, int l) {
    return __int_as_float(__builtin_amdgcn_readlane(__float_as_int(x), l));
}

#define DPP_X1 0xB1   // quad_perm [1,0,3,2]  : lane^1
#define DPP_X2 0x4E   // quad_perm [2,3,0,1]  : lane^2
#define DPP_X3 0x1B   // quad_perm [3,2,1,0]  : lane^3
#define DPP_X7 0x141  // row_half_mirror      : lane^7
#define DPP_X8 0x128  // row_ror:8            : lane^8

__global__ __launch_bounds__(64, 1) void spdlog_onesided(
    const float* __restrict__ S, float* __restrict__ Out, int nmat) {
    __shared__ float X[64][64];  // 16 KB, reconstruction only
    const int lane = threadIdx.x;
    const int b = blockIdx.x;
    if (b >= nmat) return;
    const float* Sb = S + (size_t)b * 4096;
    float* Ob = Out + (size_t)b * 4096;

    // ---- load column `lane`: rows (2k,2k+1) -> packed pair (coalesced)
    v2f g2[32];
    #pragma unroll 32
    for (int k = 0; k < 32; ++k) {
        v2f t;
        t.x = Sb[(2 * k) * 64 + lane];
        t.y = Sb[(2 * k + 1) * 64 + lane];
        g2[k] = t;
    }
    float gam = 1.0f;  // true column = sqrt(gam) * ghat

    #pragma unroll 1
    for (int sweep = 0; sweep < NSWEEP_MAX; ++sweep) {
        // ---- rescale to gam = 1 (no-op on sweep 0: mul by 1)
        {
            const float sg = __builtin_amdgcn_sqrtf(gam);
            const v2f sg2 = {sg, sg};
            #pragma unroll 32
            for (int k = 0; k < 32; ++k) g2[k] *= sg2;
            gam = 1.0f;
        }
        // ---- fresh true diagonal d = <ghat,ghat> (gam==1), fixed order
        float d;
        {
            v2f d0 = {0.f, 0.f}, d1 = {0.f, 0.f};
            v2f d2 = {0.f, 0.f}, d3 = {0.f, 0.f};
            #pragma unroll 8
            for (int k = 0; k < 32; k += 4) {
                d0 = pkfma(g2[k + 0], g2[k + 0], d0);
                d1 = pkfma(g2[k + 1], g2[k + 1], d1);
                d2 = pkfma(g2[k + 2], g2[k + 2], d2);
                d3 = pkfma(g2[k + 3], g2[k + 3], d3);
            }
            d = ((d0.x + d0.y) + (d1.x + d1.y)) +
                ((d2.x + d2.y) + (d3.x + d3.y));
        }

        // ---- initial pairing m = gray(1) = 1: fetch partner copies
        v2f pr2[32];
        #pragma unroll 32
        for (int k = 0; k < 32; ++k) pr2[k] = dppv2<DPP_X1>(g2[k]);
        float pd = dppf1<DPP_X1>(d);
        float pgam = 1.0f;  // == dpp(gam): all lanes just reset to 1

        float maxt2 = 0.0f;

        // ---- one Jacobi round (pairing m = gray(i)); straight-line body
        auto round = [&](int i) {
            if (i > 1) {
                // re-pair: next partner = current ^ delta (single bit)
                const int delta = i & (-i);
                switch (delta) {
                    case 1:
                        #pragma unroll
                        for (int k = 0; k < 32; ++k) pr2[k] = dppv2<DPP_X1>(pr2[k]);
                        pd = dppf1<DPP_X1>(pd);
                        pgam = dppf1<DPP_X1>(pgam);
                        break;
                    case 2:
                        #pragma unroll
                        for (int k = 0; k < 32; ++k) pr2[k] = dppv2<DPP_X2>(pr2[k]);
                        pd = dppf1<DPP_X2>(pd);
                        pgam = dppf1<DPP_X2>(pgam);
                        break;
                    case 4:  // XOR4 = XOR3 o XOR7
                        #pragma unroll
                        for (int k = 0; k < 32; ++k)
                            pr2[k] = dppv2<DPP_X7>(dppv2<DPP_X3>(pr2[k]));
                        pd = dppf1<DPP_X7>(dppf1<DPP_X3>(pd));
                        pgam = dppf1<DPP_X7>(dppf1<DPP_X3>(pgam));
                        break;
                    case 8:
                        #pragma unroll
                        for (int k = 0; k < 32; ++k) pr2[k] = dppv2<DPP_X8>(pr2[k]);
                        pd = dppf1<DPP_X8>(pd);
                        pgam = dppf1<DPP_X8>(pgam);
                        break;
                    case 16:
                        // hazard fence: no producer write may be scheduled
                        // adjacent to an asm permlane read (r18 root cause)
                        __builtin_amdgcn_sched_barrier(0);
                        asm volatile("s_nop 2");
                        #pragma unroll
                        for (int k = 0; k < 32; ++k) pr2[k] = swap16v2(pr2[k]);
                        pd = swap16_self(pd);
                        pgam = swap16_self(pgam);
                        __builtin_amdgcn_sched_barrier(0);
                        break;
                    default:  // 32
                        __builtin_amdgcn_sched_barrier(0);
                        asm volatile("s_nop 2");
                        #pragma unroll
                        for (int k = 0; k < 32; ++k) pr2[k] = swap32v2(pr2[k]);
                        pd = swap32_self(pd);
                        pgam = swap32_self(pgam);
                        __builtin_amdgcn_sched_barrier(0);
                        break;
                }
            }
            const int m = i ^ (i >> 1);
            const int xl = lane ^ m;
            const bool isLow = lane < xl;
            // ---- unscaled Gram cross term (pair-symmetric packed fma)
            v2f a0 = {0.f, 0.f}, a1 = {0.f, 0.f};
            v2f a2 = {0.f, 0.f}, a3 = {0.f, 0.f};
            #pragma unroll 8
            for (int k = 0; k < 32; k += 4) {
                a0 = pkfma(g2[k + 0], pr2[k + 0], a0);
                a1 = pkfma(g2[k + 1], pr2[k + 1], a1);
                a2 = pkfma(g2[k + 2], pr2[k + 2], a2);
                a3 = pkfma(g2[k + 3], pr2[k + 3], a3);
            }
            const float dpq_hat = ((a0.x + a0.y) + (a1.x + a1.y)) +
                                  ((a2.x + a2.y) + (a3.x + a3.y));
            // true dpq: gam*pgam commutes -> identical bits on both lanes
            const float sqg = __builtin_amdgcn_sqrtf(gam * pgam);
            const float dpq = sqg * dpq_hat;
            const float t2 = dpq * dpq * __builtin_amdgcn_rcpf(d * pd);
            maxt2 = fmaxf(maxt2, t2);
            // ---- wave-uniform skip (no rotation: scales/chain unchanged)
            if (__all(t2 < T2_TOL)) return;
            // ---- canonical rotation, true space (identical on both lanes)
            const float d_lo = isLow ? d : pd;
            const float d_hi = isLow ? pd : d;
            const float tau = (d_hi - d_lo) * __builtin_amdgcn_rcpf(2.0f * dpq);
            const float sq = __builtin_amdgcn_sqrtf(fmaf(tau, tau, 1.0f));
            float tt = __builtin_amdgcn_rcpf(fabsf(tau) + sq);
            tt = copysignf(tt, tau);
            float ccsq = __builtin_amdgcn_rcpf(fmaf(tt, tt, 1.0f));
            const bool tiny = fabsf(dpq) < 1e-30f;
            tt = tiny ? 0.0f : tt;
            ccsq = tiny ? 1.0f : ccsq;
            const float t_own = isLow ? tt : -tt;
            // fast-Givens coefficients (be_p == al_q bitwise, see header)
            const float al = -t_own * __builtin_amdgcn_sqrtf(
                                          pgam * __builtin_amdgcn_rcpf(gam));
            const float be = t_own * __builtin_amdgcn_sqrtf(
                                         gam * __builtin_amdgcn_rcpf(pgam));
            // true-diagonal updates (own exact; partner mirrors bitwise)
            const float pdn = fmaf(t_own, dpq, pd);
            d = fmaf(-t_own, dpq, d);
            pd = pdn;
            gam *= ccsq;
            pgam *= ccsq;
            // ---- fast-Givens update: 1 pk_fma per v2f per column
            const v2f al2 = {al, al};
            const v2f be2 = {be, be};
            #pragma unroll 16
            for (int k = 0; k < 32; k += 2) {
                const v2f go0 = g2[k + 0];
                const v2f go1 = g2[k + 1];
                g2[k + 0] = pkfma(al2, pr2[k + 0], g2[k + 0]);
                g2[k + 1] = pkfma(al2, pr2[k + 1], g2[k + 1]);
                pr2[k + 0] = pkfma(be2, go0, pr2[k + 0]);
                pr2[k + 1] = pkfma(be2, go1, pr2[k + 1]);
            }
        };

        // segment 1: rounds 1..31 (scale decay bounded by 2^-31)
        #pragma unroll 1
        for (int i = 1; i < 32; ++i) round(i);
        // mid-sweep rescale, straight-line; mirrored on the partner copy.
        // The following round(32)'s swap block opens with a fence, so these
        // writes can never be scheduled adjacent to the swap reads.
        {
            const float sg = __builtin_amdgcn_sqrtf(gam);
            const float sp = __builtin_amdgcn_sqrtf(pgam);
            const v2f sg2 = {sg, sg}, sp2 = {sp, sp};
            #pragma unroll 16
            for (int k = 0; k < 32; ++k) {
                g2[k] *= sg2;
                pr2[k] *= sp2;
            }
            gam = 1.0f;
            pgam = 1.0f;
        }
        // segment 2: rounds 32..63
        #pragma unroll 1
        for (int i = 32; i < 64; ++i) round(i);

        // ---- wave max of maxt2
        maxt2 = fmaxf(maxt2, __shfl_xor(maxt2, 1));
        maxt2 = fmaxf(maxt2, __shfl_xor(maxt2, 2));
        maxt2 = fmaxf(maxt2, __shfl_xor(maxt2, 4));
        maxt2 = fmaxf(maxt2, __shfl_xor(maxt2, 8));
        maxt2 = fmaxf(maxt2, __shfl_xor(maxt2, 16));
        maxt2 = fmaxf(maxt2, __shfl_xor(maxt2, 32));
        if (maxt2 < T2_TOL) break;  // wave-uniform
    }

    // ---- eigenvalue: lambda^2 = gam * <ghat,ghat>; U col = ghat/|ghat|
    float nh;
    {
        v2f d0 = {0.f, 0.f}, d1 = {0.f, 0.f};
        #pragma unroll 16
        for (int k = 0; k < 32; k += 2) {
            d0 = pkfma(g2[k + 0], g2[k + 0], d0);
            d1 = pkfma(g2[k + 1], g2[k + 1], d1);
        }
        nh = (d0.x + d0.y) + (d1.x + d1.y);
    }
    const float dfin = gam * nh;
    const float w = 0.5f * logf(fmaxf(dfin, EPS2));
    const float rs = __builtin_amdgcn_rsqf(fmaxf(nh, 1e-20f));

    // ---- reconstruction: O = U diag(w) U^T
    #pragma unroll 32
    for (int k = 0; k < 32; ++k) {
        X[2 * k + 0][lane] = g2[k].x * rs;  // lane-private column
        X[2 * k + 1][lane] = g2[k].y * rs;
    }
    __syncthreads();
    float uw[64];
    {
        const float4* rowp = (const float4*)&X[lane][0];  // own row of U
        #pragma unroll 16
        for (int gq = 0; gq < 16; ++gq) {
            const float4 q = rowp[gq];
            uw[4 * gq + 0] = q.x;
            uw[4 * gq + 1] = q.y;
            uw[4 * gq + 2] = q.z;
            uw[4 * gq + 3] = q.w;
        }
    }
    #pragma unroll 64
    for (int c = 0; c < 64; ++c) uw[c] *= rdlane_f(w, c);
    #pragma unroll 2
    for (int i = 0; i < 64; ++i) {
        const float4* Urow = (const float4*)&X[i][0];  // wave-uniform: bcast
        float acc = 0.0f;
        #pragma unroll 16
        for (int gq = 0; gq < 16; ++gq) {
            const float4 q = Urow[gq];
            acc = fmaf(q.x, uw[4 * gq + 0], acc);
            acc = fmaf(q.y, uw[4 * gq + 1], acc);
            acc = fmaf(q.z, uw[4 * gq + 2], acc);
            acc = fmaf(q.w, uw[4 * gq + 3], acc);
        }
        Ob[i * 64 + lane] = acc;
    }
}

extern "C" void kernel_launch(void* const* d_in, const int* in_sizes, int n_in,
                              void* d_out, int out_size, void* d_ws, size_t ws_size,
                              hipStream_t stream) {
    const float* S = (const float*)d_in[0];
    float* Out = (float*)d_out;
    const int nmat = in_sizes[0] / 4096;
    spdlog_onesided<<<nmat, 64, 0, stream>>>(S, Out, nmat);
}

// Round 20
// 3601.281 us; speedup vs baseline: 19.2207x; 19.2207x over previous
//
#include <hip/hip_runtime.h>
#include <math.h>

#define NSWEEP_MAX 16
#define T2_TOL 2e-7f    // validated r12-r16: output err ~7e-3 << 0.066
#define EPS2 1e-10f     // lambda clamp 1e-5 => lambda^2 clamp 1e-10

// FINAL (r16 restore): One-sided Jacobi on G = S (SPD), one 64-lane wave
// per 64x64 matrix, lane l holds column l. Packed-fp32 dot/update
// (v_pk_fma_f32 via <2 x float> elementwise fma — gfx950's f32 peak is
// 2x-packed), Gray-code pairing with a maintained partner copy, tie-safe
// canonical rotations. Measured 3.62ms, absmax 0.015625, VALUBusy 88%.
//
// Post-session ledger of rejected "improvements" (all measured):
//  - inline-asm forced residency: r13 7.4ms (serialized), r14 NaN (DPP
//    hazard invisible to post-RA recognizer inside asm).
//  - 2-wave/matrix row split: r12 6.3ms (per-round barrier latency).
//  - fast-Givens scaled columns (halved update ops): r17/r19 68ms
//    (allocator scratch-spill of the 64-reg arrays; r18 corrupt).
//
// GRAY-CODE pairing (r11): rounds m_i = i^(i>>1); consecutive pairings
// differ by one bit delta -> re-pair = 1-2 op XOR-delta lane permute of
// pr (DPP quad_perm 0xB1/0x4E/0x1B, row_half_mirror 0x141, row_ror:8
// 0x128; v_permlane16/32_swap self-swap == XOR16/32 — HW-verified r9/r10).
// pr' = cc*pr - es*g_old after each rotation keeps pr == g_{l^m} bitwise.
//
// BITWISE pair-consistency: packed fma is elementwise IEEE; dpq via
// commuted fma, fixed-order horizontal reduce -> identical bits on both
// pair lanes; canonical tau = (d_hi-d_lo)*rcp(2dpq); es/t_own sign-split
// by isLow; pr/pd updates are exact negation-mirrors of the partner's.

typedef float v2f __attribute__((ext_vector_type(2)));

__device__ __forceinline__ v2f pkfma(v2f a, v2f b, v2f c) {
    return __builtin_elementwise_fma(a, b, c);
}

template <int CTRL>
__device__ __forceinline__ int dpp1(int x) {
    return __builtin_amdgcn_update_dpp(0, x, CTRL, 0xF, 0xF, true);
}
template <int CTRL>
__device__ __forceinline__ float dppf1(float x) {
    return __int_as_float(dpp1<CTRL>(__float_as_int(x)));
}
template <int CTRL>
__device__ __forceinline__ v2f dppv2(v2f x) {
    v2f r;
    r.x = dppf1<CTRL>(x.x);
    r.y = dppf1<CTRL>(x.y);
    return r;
}
__device__ __forceinline__ float swap16_self(float x) {
    asm("v_permlane16_swap_b32 %0, %0" : "+v"(x));
    return x;  // x[lane] = old x[lane^16]
}
__device__ __forceinline__ float swap32_self(float x) {
    asm("v_permlane32_swap_b32 %0, %0" : "+v"(x));
    return x;  // x[lane] = old x[lane^32]
}
__device__ __forceinline__ v2f swap16v2(v2f x) {
    v2f r;
    r.x = swap16_self(x.x);
    r.y = swap16_self(x.y);
    return r;
}
__device__ __forceinline__ v2f swap32v2(v2f x) {
    v2f r;
    r.x = swap32_self(x.x);
    r.y = swap32_self(x.y);
    return r;
}
__device__ __forceinline__ float rdlane_f(float x, int l) {
    return __int_as_float(__builtin_amdgcn_readlane(__float_as_int(x), l));
}

#define DPP_X1 0xB1   // quad_perm [1,0,3,2]  : lane^1
#define DPP_X2 0x4E   // quad_perm [2,3,0,1]  : lane^2
#define DPP_X3 0x1B   // quad_perm [3,2,1,0]  : lane^3
#define DPP_X7 0x141  // row_half_mirror      : lane^7
#define DPP_X8 0x128  // row_ror:8            : lane^8

__global__ __launch_bounds__(64, 2) void spdlog_onesided(
    const float* __restrict__ S, float* __restrict__ Out, int nmat) {
    __shared__ float X[64][64];  // 16 KB, reconstruction only
    const int lane = threadIdx.x;
    const int b = blockIdx.x;
    if (b >= nmat) return;
    const float* Sb = S + (size_t)b * 4096;
    float* Ob = Out + (size_t)b * 4096;

    // ---- load column `lane`: rows (2k,2k+1) -> packed pair (coalesced)
    v2f g2[32];
    #pragma unroll 32
    for (int k = 0; k < 32; ++k) {
        v2f t;
        t.x = Sb[(2 * k) * 64 + lane];
        t.y = Sb[(2 * k + 1) * 64 + lane];
        g2[k] = t;
    }

    float dpp = 0.0f;

    #pragma unroll 1
    for (int sweep = 0; sweep < NSWEEP_MAX; ++sweep) {
        // refresh Gram diagonal from actual column (packed, fixed order)
        {
            v2f d0 = {0.f, 0.f}, d1 = {0.f, 0.f};
            v2f d2 = {0.f, 0.f}, d3 = {0.f, 0.f};
            #pragma unroll 8
            for (int k = 0; k < 32; k += 4) {
                d0 = pkfma(g2[k + 0], g2[k + 0], d0);
                d1 = pkfma(g2[k + 1], g2[k + 1], d1);
                d2 = pkfma(g2[k + 2], g2[k + 2], d2);
                d3 = pkfma(g2[k + 3], g2[k + 3], d3);
            }
            dpp = ((d0.x + d0.y) + (d1.x + d1.y)) +
                  ((d2.x + d2.y) + (d3.x + d3.y));
        }

        // ---- initial pairing m = gray(1) = 1: fetch partner copy
        v2f pr2[32];
        #pragma unroll 32
        for (int k = 0; k < 32; ++k) pr2[k] = dppv2<DPP_X1>(g2[k]);
        float pd = dppf1<DPP_X1>(dpp);

        float maxt2 = 0.0f;
        #pragma unroll 1
        for (int i = 1; i < 64; ++i) {
            if (i > 1) {
                // re-pair: next partner = current ^ delta (single bit)
                const int delta = i & (-i);
                switch (delta) {
                    case 1:
                        #pragma unroll
                        for (int k = 0; k < 32; ++k) pr2[k] = dppv2<DPP_X1>(pr2[k]);
                        pd = dppf1<DPP_X1>(pd);
                        break;
                    case 2:
                        #pragma unroll
                        for (int k = 0; k < 32; ++k) pr2[k] = dppv2<DPP_X2>(pr2[k]);
                        pd = dppf1<DPP_X2>(pd);
                        break;
                    case 4:  // XOR4 = XOR3 o XOR7
                        #pragma unroll
                        for (int k = 0; k < 32; ++k)
                            pr2[k] = dppv2<DPP_X7>(dppv2<DPP_X3>(pr2[k]));
                        pd = dppf1<DPP_X7>(dppf1<DPP_X3>(pd));
                        break;
                    case 8:
                        #pragma unroll
                        for (int k = 0; k < 32; ++k) pr2[k] = dppv2<DPP_X8>(pr2[k]);
                        pd = dppf1<DPP_X8>(pd);
                        break;
                    case 16:
                        #pragma unroll
                        for (int k = 0; k < 32; ++k) pr2[k] = swap16v2(pr2[k]);
                        pd = swap16_self(pd);
                        break;
                    default:  // 32
                        #pragma unroll
                        for (int k = 0; k < 32; ++k) pr2[k] = swap32v2(pr2[k]);
                        pd = swap32_self(pd);
                        break;
                }
            }
            const int m = i ^ (i >> 1);
            const int xl = lane ^ m;
            const bool isLow = lane < xl;
            // ---- packed Gram cross term (pair-symmetric: elementwise fma,
            // commuted products, same order on both pair lanes)
            v2f a0 = {0.f, 0.f}, a1 = {0.f, 0.f};
            v2f a2 = {0.f, 0.f}, a3 = {0.f, 0.f};
            #pragma unroll 8
            for (int k = 0; k < 32; k += 4) {
                a0 = pkfma(g2[k + 0], pr2[k + 0], a0);
                a1 = pkfma(g2[k + 1], pr2[k + 1], a1);
                a2 = pkfma(g2[k + 2], pr2[k + 2], a2);
                a3 = pkfma(g2[k + 3], pr2[k + 3], a3);
            }
            const float dpq = ((a0.x + a0.y) + (a1.x + a1.y)) +
                              ((a2.x + a2.y) + (a3.x + a3.y));
            const float t2 = dpq * dpq * __builtin_amdgcn_rcpf(dpp * pd);
            maxt2 = fmaxf(maxt2, t2);
            // ---- wave-uniform skip when every pair in this round converged
            if (__all(t2 < T2_TOL)) continue;
            // ---- canonical rotation (identical bits on both lanes)
            const float d_lo = isLow ? dpp : pd;
            const float d_hi = isLow ? pd : dpp;
            const float tau = (d_hi - d_lo) * __builtin_amdgcn_rcpf(2.0f * dpq);
            const float sq = __builtin_amdgcn_sqrtf(fmaf(tau, tau, 1.0f));
            float tt = __builtin_amdgcn_rcpf(fabsf(tau) + sq);
            tt = copysignf(tt, tau);
            float cc = __builtin_amdgcn_rsqf(fmaf(tt, tt, 1.0f));
            float ss = tt * cc;
            const bool tiny = fabsf(dpq) < 1e-30f;
            cc = tiny ? 1.0f : cc;
            ss = tiny ? 0.0f : ss;
            tt = tiny ? 0.0f : tt;
            const float es = isLow ? -ss : ss;
            const float t_own = isLow ? tt : -tt;
            // diagonal updates (own exact; partner mirrors bitwise)
            const float pdn = fmaf(t_own, dpq, pd);
            dpp = fmaf(-t_own, dpq, dpp);
            pd = pdn;
            // ---- packed rotate own column AND maintain partner copy:
            //   g'  = cc*g  + es*pr        (own update)
            //   pr' = cc*pr - es*g_old     (== partner's own update, bitwise)
            const v2f cc2 = {cc, cc};
            const v2f es2 = {es, es};
            const v2f nes2 = {-es, -es};
            #pragma unroll 16
            for (int k = 0; k < 32; k += 2) {
                const v2f go0 = g2[k + 0];
                const v2f go1 = g2[k + 1];
                g2[k + 0] = pkfma(cc2, go0, es2 * pr2[k + 0]);
                g2[k + 1] = pkfma(cc2, go1, es2 * pr2[k + 1]);
                pr2[k + 0] = pkfma(cc2, pr2[k + 0], nes2 * go0);
                pr2[k + 1] = pkfma(cc2, pr2[k + 1], nes2 * go1);
            }
        }
        // ---- wave max of maxt2
        maxt2 = fmaxf(maxt2, __shfl_xor(maxt2, 1));
        maxt2 = fmaxf(maxt2, __shfl_xor(maxt2, 2));
        maxt2 = fmaxf(maxt2, __shfl_xor(maxt2, 4));
        maxt2 = fmaxf(maxt2, __shfl_xor(maxt2, 8));
        maxt2 = fmaxf(maxt2, __shfl_xor(maxt2, 16));
        maxt2 = fmaxf(maxt2, __shfl_xor(maxt2, 32));
        if (maxt2 < T2_TOL) break;  // wave-uniform
    }

    // ---- fresh column norm^2 -> eigenvalue; clamp matches ref (on lambda)
    float dfin;
    {
        v2f d0 = {0.f, 0.f}, d1 = {0.f, 0.f};
        #pragma unroll 16
        for (int k = 0; k < 32; k += 2) {
            d0 = pkfma(g2[k + 0], g2[k + 0], d0);
            d1 = pkfma(g2[k + 1], g2[k + 1], d1);
        }
        dfin = (d0.x + d0.y) + (d1.x + d1.y);
    }
    const float w = 0.5f * logf(fmaxf(dfin, EPS2));
    const float rs = __builtin_amdgcn_rsqf(fmaxf(dfin, 1e-20f));

    // ---- reconstruction: O = U diag(w) U^T, U columns = g*rs
    #pragma unroll 32
    for (int k = 0; k < 32; ++k) {
        X[2 * k + 0][lane] = g2[k].x * rs;  // lane-private column
        X[2 * k + 1][lane] = g2[k].y * rs;
    }
    __syncthreads();
    float uw[64];
    {
        const float4* rowp = (const float4*)&X[lane][0];  // own row of U
        #pragma unroll 16
        for (int gq = 0; gq < 16; ++gq) {
            const float4 q = rowp[gq];
            uw[4 * gq + 0] = q.x;
            uw[4 * gq + 1] = q.y;
            uw[4 * gq + 2] = q.z;
            uw[4 * gq + 3] = q.w;
        }
    }
    #pragma unroll 64
    for (int c = 0; c < 64; ++c) uw[c] *= rdlane_f(w, c);
    #pragma unroll 2
    for (int i = 0; i < 64; ++i) {
        const float4* Urow = (const float4*)&X[i][0];  // wave-uniform: bcast
        float acc = 0.0f;
        #pragma unroll 16
        for (int gq = 0; gq < 16; ++gq) {
            const float4 q = Urow[gq];
            acc = fmaf(q.x, uw[4 * gq + 0], acc);
            acc = fmaf(q.y, uw[4 * gq + 1], acc);
            acc = fmaf(q.z, uw[4 * gq + 2], acc);
            acc = fmaf(q.w, uw[4 * gq + 3], acc);
        }
        Ob[i * 64 + lane] = acc;
    }
}

extern "C" void kernel_launch(void* const* d_in, const int* in_sizes, int n_in,
                              void* d_out, int out_size, void* d_ws, size_t ws_size,
                              hipStream_t stream) {
    const float* S = (const float*)d_in[0];
    float* Out = (float*)d_out;
    const int nmat = in_sizes[0] / 4096;
    spdlog_onesided<<<nmat, 64, 0, stream>>>(S, Out, nmat);
}